// Round 6
// baseline (750.870 us; speedup 1.0000x reference)
//
#include <hip/hip_runtime.h>
#include <stdint.h>

typedef int v4i  __attribute__((ext_vector_type(4)));
typedef int v16i __attribute__((ext_vector_type(16)));

#define T_TOK 8192
#define H_DIM 1024
#define F_DIM 3584
#define N_EXP 8

// ---------------- workspace layout (bytes) ----------------
// BK=64 slabs: 8 KB = [rg(4)][c16(4)][r(32)] v4i; element (row=rg*32+r, k=c16*16..+16).
#define W13T_OFF  0u               // [e][ft(28)][kt64(16)][mat(2)][8KB] = 58,720,256
#define XQ_OFF    58720256u        // [token][1024]                       8,388,608
#define W2T_OFF   67108864u        // [e][ht(8)][kt64(56)][8KB]          29,360,128
#define GBT_OFF   96501760u        // [tile(136)][kt64(56)][8KB]         62,390,272
#define XS_OFF    158892032u
#define LIST_OFF  158924800u
#define TW_OFF    159186944u
#define TSLOT_OFF 159449088u
#define CNT_OFF   159514624u
#define OFFS_OFF  159514656u
#define NT_OFF    159514688u
#define WLIST_OFF 159514752u
// rinfo/wp/bhist ALIAS the head of gbt: written by router, consumed by
// planner/scatter, dead before gemm1 (the gbt producer) launches.
#define RINFO_OFF 96501760u        // [8192] int  (e0|e1<<3|r0<<6|r1<<10)
#define WP_OFF    96534528u        // [8192] float2
#define BHIST_OFF 96600064u        // [1024][8] int
// xg (slot-gathered A tiles, slab layout) ALIASES w2t: alive only between
// gather and gemm1; convert2 (w2t producer) runs after gemm1.
#define XG_OFF    67108864u        // [tile(136)][kt64(16)][8KB] = 17,825,792
#define XSG_OFF   84934656u        // [tile(136)][128] f32
// YBUF aliases [w13t|xq] = 67,108,864 B exactly; both dead after gemm1.
#define YBUF_OFF  0u

__device__ __forceinline__ void async16(const void* g, void* l) {
    __builtin_amdgcn_global_load_lds(
        (const __attribute__((address_space(1))) unsigned int*)g,
        (__attribute__((address_space(3))) unsigned int*)l, 16, 0, 0);
}

__device__ __forceinline__ int pack4(float a, float b, float c, float d) {
    int ia = (int)(signed char)(int)a, ib = (int)(signed char)(int)b;
    int ic = (int)(signed char)(int)c, id = (int)(signed char)(int)d;
    return (ia & 0xff) | ((ib & 0xff) << 8) | ((ic & 0xff) << 16) | (id << 24);
}

// ---------------- weight fp32 -> int8 tiled repack (BK=64 slabs) ----------------
__global__ __launch_bounds__(256) void convert13_kernel(
    const float* __restrict__ w1, const float* __restrict__ w3,
    v4i* __restrict__ w13t)
{
    int d = blockIdx.x * 256 + threadIdx.x;       // 14336 blocks: 3,670,016 v4i
    int wi = d & 511;
    int rg = wi >> 7, c16 = (wi >> 5) & 3, r = wi & 31;
    int si = d >> 9;
    int mat = si & 1, kt = (si >> 1) & 15, rest = si >> 5;  // e*28+ft
    int e = rest / 28, ft = rest - e * 28;
    const float* s = (mat ? w3 : w1)
      + ((size_t)(e * F_DIM + ft * 128 + rg * 32 + r)) * H_DIM
      + kt * 64 + c16 * 16;
    const float4* sv = (const float4*)s;
    float4 f0 = sv[0], f1 = sv[1], f2 = sv[2], f3 = sv[3];
    v4i o;
    o.x = pack4(f0.x, f0.y, f0.z, f0.w);
    o.y = pack4(f1.x, f1.y, f1.z, f1.w);
    o.z = pack4(f2.x, f2.y, f2.z, f2.w);
    o.w = pack4(f3.x, f3.y, f3.z, f3.w);
    w13t[d] = o;
}

__global__ __launch_bounds__(256) void convert2_kernel(
    const float* __restrict__ w2, v4i* __restrict__ w2t)
{
    int d = blockIdx.x * 256 + threadIdx.x;       // 7168 blocks: 1,835,008 v4i
    int wi = d & 511;
    int rg = wi >> 7, c16 = (wi >> 5) & 3, r = wi & 31;
    int si = d >> 9;
    int kt = si % 56, q = si / 56;
    int ht = q & 7, e = q >> 3;
    const float* s = w2 + ((size_t)(e * H_DIM + ht * 128 + rg * 32 + r)) * F_DIM
          + kt * 64 + c16 * 16;
    const float4* sv = (const float4*)s;
    float4 f0 = sv[0], f1 = sv[1], f2 = sv[2], f3 = sv[3];
    v4i o;
    o.x = pack4(f0.x, f0.y, f0.z, f0.w);
    o.y = pack4(f1.x, f1.y, f1.z, f1.w);
    o.z = pack4(f2.x, f2.y, f2.z, f2.w);
    o.w = pack4(f3.x, f3.y, f3.z, f3.w);
    w2t[d] = o;
}

// ---------------- router: 1 wave per token, shfl butterfly, no global atomics ----------------
// block = 4 waves x 2 tokens = 8 tokens; grid 1024. Per-block histogram -> bhist.
__global__ __launch_bounds__(256, 4) void router_kernel(
    const float* __restrict__ x, const float* __restrict__ gw,
    int8_t* __restrict__ xq, float* __restrict__ xs,
    int* __restrict__ bhist, int* __restrict__ rinfo, float2* __restrict__ wp,
    float* __restrict__ logits_out)
{
    const int t = threadIdx.x, lane = t & 63, wv = t >> 6;
    __shared__ int lhist[8];
    if (t < 8) lhist[t] = 0;
    __syncthreads();
    const float4* gw4 = (const float4*)gw;
#pragma unroll 1
    for (int i = 0; i < 2; i++) {
        const int token = blockIdx.x * 8 + wv * 2 + i;
        const float4* xrow = (const float4*)(x + (size_t)token * H_DIM);
        float4 xv[4];
#pragma unroll
        for (int j = 0; j < 4; j++) xv[j] = xrow[j * 64 + lane];
        float am = 0.0f;
#pragma unroll
        for (int j = 0; j < 4; j++)
            am = fmaxf(am, fmaxf(fmaxf(fabsf(xv[j].x), fabsf(xv[j].y)),
                                 fmaxf(fabsf(xv[j].z), fabsf(xv[j].w))));
        float l[8];
#pragma unroll
        for (int e = 0; e < 8; e++) {
            float d = 0.0f;
#pragma unroll
            for (int j = 0; j < 4; j++) {
                float4 g = gw4[e * 256 + j * 64 + lane];
                d += xv[j].x * g.x + xv[j].y * g.y + xv[j].z * g.z + xv[j].w * g.w;
            }
            l[e] = d;
        }
        // 64-lane butterfly: all lanes end with full sums / max (bitwise identical)
#pragma unroll
        for (int m = 1; m < 64; m <<= 1) {
#pragma unroll
            for (int e = 0; e < 8; e++) l[e] += __shfl_xor(l[e], m, 64);
            am = fmaxf(am, __shfl_xor(am, m, 64));
        }
        // top-2 on logits (monotone in softmax probs); static indexing only
        float v0 = l[0]; int i0 = 0;
#pragma unroll
        for (int e = 1; e < 8; e++) if (l[e] > v0) { v0 = l[e]; i0 = e; }
        float v1 = -3.4e38f; int i1 = 0;
#pragma unroll
        for (int e = 0; e < 8; e++) if (e != i0 && l[e] > v1) { v1 = l[e]; i1 = e; }
        const float tt = __expf(v1 - v0);
        const float w0 = 1.0f / (1.0f + tt);
        const float w1 = tt * w0;
        const float s = fmaxf(am, 1e-8f) / 127.0f;
        const float rs = 1.0f / s;
        int8_t* xqr = xq + (size_t)token * H_DIM;
#pragma unroll
        for (int j = 0; j < 4; j++) {
            char4 c;
            c.x = (signed char)fminf(fmaxf(rintf(xv[j].x * rs), -127.0f), 127.0f);
            c.y = (signed char)fminf(fmaxf(rintf(xv[j].y * rs), -127.0f), 127.0f);
            c.z = (signed char)fminf(fmaxf(rintf(xv[j].z * rs), -127.0f), 127.0f);
            c.w = (signed char)fminf(fmaxf(rintf(xv[j].w * rs), -127.0f), 127.0f);
            ((char4*)xqr)[j * 64 + lane] = c;
        }
        if (lane == 0) {
            xs[token] = s;
#pragma unroll
            for (int e = 0; e < 8; e++) logits_out[(size_t)token * 8 + e] = l[e];
            int r0 = atomicAdd(&lhist[i0], 1);   // LDS atomic, per-block only
            int r1 = atomicAdd(&lhist[i1], 1);
            rinfo[token] = i0 | (i1 << 3) | (r0 << 6) | (r1 << 10);
            wp[token] = make_float2(w0, w1);
        }
    }
    __syncthreads();
    if (t < 8) bhist[blockIdx.x * 8 + t] = lhist[t];
}

// ---------------- planner: parallel scan of bhist -> expert-local prefixes ----------------
__global__ __launch_bounds__(256) void planner_kernel(
    int* __restrict__ bhist, int* __restrict__ cnt, int* __restrict__ offs,
    int* __restrict__ ntile, int* __restrict__ wlist)
{
    __shared__ int sm[8 * 1060];   // [e][b + b/32 pad]
    __shared__ int tot[8];
    const int t = threadIdx.x;
#pragma unroll
    for (int k = 0; k < 32; k++) {
        int idx = k * 256 + t;
        int v = bhist[idx];
        int e = idx & 7, b = idx >> 3;
        sm[e * 1060 + b + (b >> 5)] = v;
    }
    __syncthreads();
    const int e = t >> 5, sub = t & 31;
    int* seg = sm + e * 1060 + sub * 33;     // b=sub*32+i -> sub*33+i
    int run = 0;
#pragma unroll
    for (int i = 0; i < 32; i++) { int v = seg[i]; seg[i] = run; run += v; }
    int inc = run;
#pragma unroll
    for (int d = 1; d < 32; d <<= 1) {
        int u = __shfl_up(inc, d, 32);
        if (sub >= d) inc += u;
    }
    const int segbase = inc - run;
    if (sub == 31) tot[e] = inc;
#pragma unroll
    for (int i = 0; i < 32; i++) seg[i] += segbase;
    __syncthreads();
    if (t == 0) {
        int s = 0, nt = 0;
        for (int ee = 0; ee < 8; ee++) {
            offs[ee] = s;
            int c = tot[ee];
            cnt[ee] = c;
            s += c;
            int tc = (c + 127) >> 7;
            for (int m = 0; m < tc; m++) wlist[nt++] = (ee << 8) | m;
        }
        *ntile = nt;
    }
#pragma unroll
    for (int k = 0; k < 32; k++) {
        int idx = k * 256 + t;
        int ee = idx & 7, b = idx >> 3;
        bhist[idx] = sm[ee * 1060 + b + (b >> 5)];
    }
}

// ---------------- scatter: finalize list/tw/tslot from prefixes ----------------
__global__ __launch_bounds__(256) void scatter_kernel(
    const int* __restrict__ bhist, const int* __restrict__ rinfo,
    const float2* __restrict__ wp, int* __restrict__ list,
    float* __restrict__ tw, int* __restrict__ tslot)
{
    const int token = blockIdx.x * 256 + threadIdx.x;
    const int ri = rinfo[token];
    const float2 wpr = wp[token];
    const int b = token >> 3;
    const int e0 = ri & 7, e1 = (ri >> 3) & 7;
    const int r0 = (ri >> 6) & 15, r1 = (ri >> 10) & 15;
    const int p0 = bhist[b * 8 + e0] + r0;
    const int p1 = bhist[b * 8 + e1] + r1;
    list[e0 * T_TOK + p0] = token;  tw[e0 * T_TOK + p0] = wpr.x;
    list[e1 * T_TOK + p1] = token;  tw[e1 * T_TOK + p1] = wpr.y;
    tslot[token * 2 + 0] = (e0 << 16) | p0;
    tslot[token * 2 + 1] = (e1 << 16) | p1;
}

// ---------------- activation gather: slot-ordered A tiles in slab layout ----------------
__global__ __launch_bounds__(256) void gather_kernel(
    const int8_t* __restrict__ xq, const float* __restrict__ xs,
    const int* __restrict__ cnt, const int* __restrict__ ntile_p,
    const int* __restrict__ wlist, const int* __restrict__ list,
    v4i* __restrict__ xg, float* __restrict__ xsg)
{
    const int bx = blockIdx.x;
    if (bx >= *ntile_p) return;
    const int wl = wlist[bx];
    const int e = wl >> 8, mt = wl & 255;
    const int count = cnt[e];
    const int cm1 = count - 1;
    const int t = threadIdx.x;
    const int* liste = list + e * T_TOK;
    __shared__ int stok[128];
    if (t < 128) {
        int p = mt * 128 + t;
        int tok = liste[p < count ? p : cm1];
        stok[t] = tok;
        xsg[bx * 128 + t] = xs[tok];
    }
    __syncthreads();
    v4i* dslab = xg + (size_t)bx * 8192;   // 16 slabs x 512 v4i
#pragma unroll
    for (int i = 0; i < 32; i++) {
        int flat = i * 256 + t;            // [row(128)][c(64 v4i)]
        int row = flat >> 6, c = flat & 63;
        v4i v = ((const v4i*)(xq + (size_t)stok[row] * H_DIM))[c];
        int kt = c >> 2, c16 = c & 3, rg = row >> 5, r = row & 31;
        dslab[kt * 512 + rg * 128 + c16 * 32 + r] = v;
    }
}

// ---------------- grouped GEMM1: 2-buffer pipeline, BK=64, XCD-chunked (bx innermost) ----------------
// Per-XCD chunk = {bx in [xcd*17, xcd*17+17), all 28 ft}, ordered ft OUTER / bx INNER:
// the XCD's 17 xg A-tiles (2.2 MB) stay L2-resident for the chunk's lifetime, and each
// B-slab (e,ft) is reused by 17 consecutive (concurrent) blocks -> fetched ~once.
__global__ __launch_bounds__(256, 3) void gemm1_kernel(
    const v4i* __restrict__ xg, const float* __restrict__ xsg,
    const v4i* __restrict__ w13t,
    const float* __restrict__ w1s, const float* __restrict__ w3s,
    const float* __restrict__ dscale,
    const int* __restrict__ cnt, const int* __restrict__ ntile_p,
    const int* __restrict__ wlist,
    int8_t* __restrict__ gbt)
{
    const int h = blockIdx.x + blockIdx.y * 136;        // 3808 = 8 * 476
    const int w476 = h >> 3;                            // position within XCD chunk
    const int ft  = w476 / 17;                          // 28 values, OUTER
    const int bxi = w476 - ft * 17;                     // 17 values, INNER
    const int bx  = (h & 7) * 17 + bxi;
    if (bx >= *ntile_p) return;
    const int wl = wlist[bx];
    const int e = wl >> 8, mt = wl & 255;
    const int count = cnt[e];
    const int t = threadIdx.x, lane = t & 63, w = t >> 6;
    const int wm = w >> 1, wn = w & 1;

    __shared__ v4i sm[3072];   // 2 buffers x [A 512 | B1 512 | B3 512] v4i = 48 KB
    char* smb = (char*)sm;

    const char* gA = (const char*)(xg + (size_t)bx * 8192) + w * 2048 + lane * 16;
    const char* gB = (const char*)(w13t + (size_t)(e * 28 + ft) * 16384) + lane * 16;
    const int wq = w * 2048;

    v16i acc1[2][2], acc3[2][2];
#pragma unroll
    for (int i = 0; i < 2; i++)
#pragma unroll
        for (int j = 0; j < 2; j++)
#pragma unroll
            for (int r = 0; r < 16; r++) { acc1[i][j][r] = 0; acc3[i][j][r] = 0; }

    auto stage = [&](int kt, int buf) {     // 6 wave-linear 1KB global_load_lds
        char* base = smb + buf * 24576;
        const char* sa = gA + kt * 8192;
        async16(sa,        base + wq);
        async16(sa + 1024, base + wq + 1024);
        const char* s1 = gB + (size_t)kt * 16384;
        async16(s1 + wq,               base + 8192 + wq);
        async16(s1 + wq + 1024,        base + 8192 + wq + 1024);
        async16(s1 + 8192 + wq,        base + 16384 + wq);
        async16(s1 + 8192 + wq + 1024, base + 16384 + wq + 1024);
    };
    auto compute = [&](int buf) {
        const v4i* S = sm + buf * 1536;
#pragma unroll
        for (int ks = 0; ks < 2; ks++) {
            const int base = (2 * ks + (lane >> 5)) * 32 + (lane & 31);
            v4i a0  = S[base + (wm * 2 + 0) * 128];
            v4i a1  = S[base + (wm * 2 + 1) * 128];
            v4i b1a = S[512 + base + (wn * 2 + 0) * 128];
            v4i b1b = S[512 + base + (wn * 2 + 1) * 128];
            v4i b3a = S[1024 + base + (wn * 2 + 0) * 128];
            v4i b3b = S[1024 + base + (wn * 2 + 1) * 128];
            acc1[0][0] = __builtin_amdgcn_mfma_i32_32x32x32_i8(a0, b1a, acc1[0][0], 0, 0, 0);
            acc1[0][1] = __builtin_amdgcn_mfma_i32_32x32x32_i8(a0, b1b, acc1[0][1], 0, 0, 0);
            acc1[1][0] = __builtin_amdgcn_mfma_i32_32x32x32_i8(a1, b1a, acc1[1][0], 0, 0, 0);
            acc1[1][1] = __builtin_amdgcn_mfma_i32_32x32x32_i8(a1, b1b, acc1[1][1], 0, 0, 0);
            acc3[0][0] = __builtin_amdgcn_mfma_i32_32x32x32_i8(a0, b3a, acc3[0][0], 0, 0, 0);
            acc3[0][1] = __builtin_amdgcn_mfma_i32_32x32x32_i8(a0, b3b, acc3[0][1], 0, 0, 0);
            acc3[1][0] = __builtin_amdgcn_mfma_i32_32x32x32_i8(a1, b3a, acc3[1][0], 0, 0, 0);
            acc3[1][1] = __builtin_amdgcn_mfma_i32_32x32x32_i8(a1, b3b, acc3[1][1], 0, 0, 0);
        }
    };

    stage(0, 0);
    for (int kt = 0; kt < 16; kt++) {
        __syncthreads();
        if (kt + 1 < 16) stage(kt + 1, (kt + 1) & 1);
        compute(kt & 1);
    }

    const float ds = dscale[e];
    const float rds = 1.0f / ds;
    int8_t* gout = gbt + (size_t)bx * 458752 + (size_t)(ft * 2 + wn) * 8192;
#pragma unroll
    for (int im = 0; im < 2; im++) {
#pragma unroll
        for (int in = 0; in < 2; in++) {
            const int fco = in * 32 + (lane & 31);
            const int fcol = ft * 128 + wn * 64 + fco;
            const float s1 = w1s[e * F_DIM + fcol];
            const float s3 = w3s[e * F_DIM + fcol];
            const int coff = ((in * 2 + ((lane & 31) >> 4)) * 32) * 16 + (lane & 15);
#pragma unroll
            for (int r = 0; r < 16; r++) {
                int row = wm * 64 + im * 32 + (r & 3) + 8 * (r >> 2) + 4 * (lane >> 5);
                int p = mt * 128 + row;
                if (p < count) {
                    float sx = xsg[bx * 128 + row];
                    float h1 = (float)acc1[im][in][r] * sx * s1;
                    float h3 = (float)acc3[im][in][r] * sx * s3;
                    float g = h1 * __builtin_amdgcn_rcpf(1.0f + __expf(-h1)) * h3;
                    float qv = fminf(fmaxf(rintf(g * rds), -127.0f), 127.0f);
                    gout[(size_t)((wm * 2 + im) * 128 + (row & 31)) * 16 + coff] = (int8_t)qv;
                }
            }
        }
    }
}

// ---------------- grouped GEMM2: 2-buffer pipeline, BK=64, XCD-chunked work remap ----------------
__global__ __launch_bounds__(256, 3) void gemm2_kernel(
    const int8_t* __restrict__ gbt, const v4i* __restrict__ w2t,
    const float* __restrict__ w2s, const float* __restrict__ dscale,
    const int* __restrict__ cnt, const int* __restrict__ offs,
    const int* __restrict__ ntile_p, const int* __restrict__ wlist,
    const float* __restrict__ tw, float* __restrict__ ybuf)
{
    const int h = blockIdx.x + blockIdx.y * 136;        // 1088 = 8 * 136
    const int wk = (h & 7) * 136 + (h >> 3);
    const int bx = wk >> 3;
    const int ht = wk & 7;
    if (bx >= *ntile_p) return;
    const int wl = wlist[bx];
    const int e = wl >> 8, mt = wl & 255;
    const int count = cnt[e];
    const int t = threadIdx.x, lane = t & 63, w = t >> 6;
    const int wm = w >> 1, wn = w & 1;

    __shared__ v4i sm[2048];   // 2 buffers x [A 512 | B 512] = 32 KB
    char* smb = (char*)sm;

    const char* gA = (const char*)gbt + (size_t)bx * 458752 + w * 2048 + lane * 16;
    const char* gB = (const char*)(w2t + (size_t)(e * 8 + ht) * 28672) + w * 2048 + lane * 16;

    v16i acc[2][2];
#pragma unroll
    for (int i = 0; i < 2; i++)
#pragma unroll
        for (int j = 0; j < 2; j++)
#pragma unroll
            for (int r = 0; r < 16; r++) acc[i][j][r] = 0;

    auto stage = [&](int kt, int buf) {
        char* base = smb + buf * 16384;
        const size_t ko = (size_t)kt * 8192;
        async16(gA + ko,        base + w * 2048);
        async16(gA + ko + 1024, base + w * 2048 + 1024);
        async16(gB + ko,        base + 8192 + w * 2048);
        async16(gB + ko + 1024, base + 8192 + w * 2048 + 1024);
    };
    auto compute = [&](int buf) {
        const v4i* S = sm + buf * 1024;
#pragma unroll
        for (int ks = 0; ks < 2; ks++) {
            const int base = (2 * ks + (lane >> 5)) * 32 + (lane & 31);
            v4i a0 = S[base + (wm * 2 + 0) * 128];
            v4i a1 = S[base + (wm * 2 + 1) * 128];
            v4i b0 = S[512 + base + (wn * 2 + 0) * 128];
            v4i b1 = S[512 + base + (wn * 2 + 1) * 128];
            acc[0][0] = __builtin_amdgcn_mfma_i32_32x32x32_i8(a0, b0, acc[0][0], 0, 0, 0);
            acc[0][1] = __builtin_amdgcn_mfma_i32_32x32x32_i8(a0, b1, acc[0][1], 0, 0, 0);
            acc[1][0] = __builtin_amdgcn_mfma_i32_32x32x32_i8(a1, b0, acc[1][0], 0, 0, 0);
            acc[1][1] = __builtin_amdgcn_mfma_i32_32x32x32_i8(a1, b1, acc[1][1], 0, 0, 0);
        }
    };

    stage(0, 0);
    for (int kt = 0; kt < 56; kt++) {
        __syncthreads();
        if (kt + 1 < 56) stage(kt + 1, (kt + 1) & 1);
        compute(kt & 1);
    }

    const float ds = dscale[e];
    const int rowbase = offs[e] + mt * 128;
#pragma unroll
    for (int im = 0; im < 2; im++) {
#pragma unroll
        for (int in = 0; in < 2; in++) {
            const int h2 = ht * 128 + wn * 64 + in * 32 + (lane & 31);
            const float sc = ds * w2s[e * H_DIM + h2];
#pragma unroll
            for (int r = 0; r < 16; r++) {
                int row = wm * 64 + im * 32 + (r & 3) + 8 * (r >> 2) + 4 * (lane >> 5);
                int p = mt * 128 + row;
                if (p < count) {
                    float rw = tw[e * T_TOK + p];
                    ybuf[(size_t)(rowbase + row) * H_DIM + h2] = (float)acc[im][in][r] * sc * rw;
                }
            }
        }
    }
}

// ---------------- combine ----------------
__global__ __launch_bounds__(256) void combine_kernel(
    const float* __restrict__ ybuf, const int* __restrict__ offs,
    const int* __restrict__ tslot, float* __restrict__ out)
{
    const int token = blockIdx.x;
    const int i = threadIdx.x;
    const int s0 = tslot[token * 2 + 0];
    const int s1 = tslot[token * 2 + 1];
    const int slot0 = offs[s0 >> 16] + (s0 & 0xffff);
    const int slot1 = offs[s1 >> 16] + (s1 & 0xffff);
    float4 a = ((const float4*)(ybuf + (size_t)slot0 * H_DIM))[i];
    float4 b = ((const float4*)(ybuf + (size_t)slot1 * H_DIM))[i];
    float4 o;
    o.x = a.x + b.x; o.y = a.y + b.y; o.z = a.z + b.z; o.w = a.w + b.w;
    ((float4*)(out + (size_t)token * H_DIM))[i] = o;
}

extern "C" void kernel_launch(void* const* d_in, const int* in_sizes, int n_in,
                              void* d_out, int out_size, void* d_ws, size_t ws_size,
                              hipStream_t stream)
{
    const float* x    = (const float*)d_in[0];
    const float* gw   = (const float*)d_in[1];
    const float* w1   = (const float*)d_in[2];
    const float* w1s  = (const float*)d_in[3];
    const float* w3   = (const float*)d_in[4];
    const float* w3s  = (const float*)d_in[5];
    const float* w2   = (const float*)d_in[6];
    const float* w2s  = (const float*)d_in[7];
    const float* dsc  = (const float*)d_in[8];

    float* out = (float*)d_out;
    float* logits_out = out + (size_t)T_TOK * H_DIM;

    char* ws = (char*)d_ws;
    v4i*    w13t = (v4i*)   (ws + W13T_OFF);
    int8_t* xq   = (int8_t*)(ws + XQ_OFF);
    v4i*    w2t  = (v4i*)   (ws + W2T_OFF);
    int8_t* gbt  = (int8_t*)(ws + GBT_OFF);
    float*  xs   = (float*) (ws + XS_OFF);
    int*    list = (int*)   (ws + LIST_OFF);
    float*  tws  = (float*) (ws + TW_OFF);
    int*    tslot= (int*)   (ws + TSLOT_OFF);
    int*    cnt  = (int*)   (ws + CNT_OFF);
    int*    offs = (int*)   (ws + OFFS_OFF);
    int*    ntile= (int*)   (ws + NT_OFF);
    int*    wlist= (int*)   (ws + WLIST_OFF);
    int*    rinfo= (int*)   (ws + RINFO_OFF);
    float2* wp   = (float2*)(ws + WP_OFF);
    int*    bhist= (int*)   (ws + BHIST_OFF);
    v4i*    xg   = (v4i*)   (ws + XG_OFF);
    float*  xsg  = (float*) (ws + XSG_OFF);
    float*  ybuf = (float*) (ws + YBUF_OFF);

    convert13_kernel<<<14336, 256, 0, stream>>>(w1, w3, w13t);
    router_kernel<<<1024, 256, 0, stream>>>(x, gw, xq, xs, bhist, rinfo, wp, logits_out);
    planner_kernel<<<1, 256, 0, stream>>>(bhist, cnt, offs, ntile, wlist);
    scatter_kernel<<<32, 256, 0, stream>>>(bhist, rinfo, wp, list, tws, tslot);
    gather_kernel<<<136, 256, 0, stream>>>(xq, xs, cnt, ntile, wlist, list, xg, xsg);
    gemm1_kernel<<<dim3(136, 28), 256, 0, stream>>>(
        xg, xsg, w13t, w1s, w3s, dsc, cnt, ntile, wlist, gbt);
    convert2_kernel<<<7168, 256, 0, stream>>>(w2, w2t);   // overwrites xg (dead)
    gemm2_kernel<<<dim3(136, 8), 256, 0, stream>>>(
        gbt, w2t, w2s, dsc, cnt, offs, ntile, wlist, tws, ybuf);
    combine_kernel<<<T_TOK, 256, 0, stream>>>(ybuf, offs, tslot, out);
}

// Round 7
// 733.422 us; speedup vs baseline: 1.0238x; 1.0238x over previous
//
#include <hip/hip_runtime.h>
#include <stdint.h>

typedef int v4i  __attribute__((ext_vector_type(4)));
typedef int v16i __attribute__((ext_vector_type(16)));

#define T_TOK 8192
#define H_DIM 1024
#define F_DIM 3584
#define N_EXP 8

// ---------------- workspace layout (bytes) ----------------
// BK=64 slabs: 8 KB = [rg(4)][c16(4)][r(32)] v4i; element (row=rg*32+r, k=c16*16..+16).
#define W13T_OFF  0u               // [e][ft(28)][kt64(16)][mat(2)][8KB] = 58,720,256
#define XQ_OFF    58720256u        // [token][1024]                       8,388,608
#define W2T_OFF   67108864u        // [e][ht(8)][kt64(56)][8KB]          29,360,128
#define GBT_OFF   96501760u        // [tile(136)][kt64(56)][8KB]         62,390,272
#define XS_OFF    158892032u
#define LIST_OFF  158924800u
#define TW_OFF    159186944u
#define TSLOT_OFF 159449088u
#define CNT_OFF   159514624u
#define OFFS_OFF  159514656u
#define NT_OFF    159514688u
#define WLIST_OFF 159514752u
// rinfo/wp/bhist ALIAS the head of gbt: written by router, consumed by
// planner/scatter, dead before gemm1 (the gbt producer) launches.
#define RINFO_OFF 96501760u        // [8192] int  (e0|e1<<3|r0<<6|r1<<10)
#define WP_OFF    96534528u        // [8192] float2
#define BHIST_OFF 96600064u        // [1024][8] int
// xg (slot-gathered A tiles, slab layout) ALIASES w2t: alive only between
// gather and gemm1; convert2 (w2t producer) runs after gemm1.
#define XG_OFF    67108864u        // [tile(136)][kt64(16)][8KB] = 17,825,792
#define XSG_OFF   84934656u        // [tile(136)][128] f32
// YBUF aliases [w13t|xq] = 67,108,864 B exactly; both dead after gemm1.
#define YBUF_OFF  0u

__device__ __forceinline__ void async16(const void* g, void* l) {
    __builtin_amdgcn_global_load_lds(
        (const __attribute__((address_space(1))) unsigned int*)g,
        (__attribute__((address_space(3))) unsigned int*)l, 16, 0, 0);
}

__device__ __forceinline__ int pack4(float a, float b, float c, float d) {
    int ia = (int)(signed char)(int)a, ib = (int)(signed char)(int)b;
    int ic = (int)(signed char)(int)c, id = (int)(signed char)(int)d;
    return (ia & 0xff) | ((ib & 0xff) << 8) | ((ic & 0xff) << 16) | (id << 24);
}

// ---------------- weight fp32 -> int8 tiled repack (BK=64 slabs) ----------------
__global__ __launch_bounds__(256) void convert13_kernel(
    const float* __restrict__ w1, const float* __restrict__ w3,
    v4i* __restrict__ w13t)
{
    int d = blockIdx.x * 256 + threadIdx.x;       // 14336 blocks: 3,670,016 v4i
    int wi = d & 511;
    int rg = wi >> 7, c16 = (wi >> 5) & 3, r = wi & 31;
    int si = d >> 9;
    int mat = si & 1, kt = (si >> 1) & 15, rest = si >> 5;  // e*28+ft
    int e = rest / 28, ft = rest - e * 28;
    const float* s = (mat ? w3 : w1)
      + ((size_t)(e * F_DIM + ft * 128 + rg * 32 + r)) * H_DIM
      + kt * 64 + c16 * 16;
    const float4* sv = (const float4*)s;
    float4 f0 = sv[0], f1 = sv[1], f2 = sv[2], f3 = sv[3];
    v4i o;
    o.x = pack4(f0.x, f0.y, f0.z, f0.w);
    o.y = pack4(f1.x, f1.y, f1.z, f1.w);
    o.z = pack4(f2.x, f2.y, f2.z, f2.w);
    o.w = pack4(f3.x, f3.y, f3.z, f3.w);
    w13t[d] = o;
}

__global__ __launch_bounds__(256) void convert2_kernel(
    const float* __restrict__ w2, v4i* __restrict__ w2t)
{
    int d = blockIdx.x * 256 + threadIdx.x;       // 7168 blocks: 1,835,008 v4i
    int wi = d & 511;
    int rg = wi >> 7, c16 = (wi >> 5) & 3, r = wi & 31;
    int si = d >> 9;
    int kt = si % 56, q = si / 56;
    int ht = q & 7, e = q >> 3;
    const float* s = w2 + ((size_t)(e * H_DIM + ht * 128 + rg * 32 + r)) * F_DIM
          + kt * 64 + c16 * 16;
    const float4* sv = (const float4*)s;
    float4 f0 = sv[0], f1 = sv[1], f2 = sv[2], f3 = sv[3];
    v4i o;
    o.x = pack4(f0.x, f0.y, f0.z, f0.w);
    o.y = pack4(f1.x, f1.y, f1.z, f1.w);
    o.z = pack4(f2.x, f2.y, f2.z, f2.w);
    o.w = pack4(f3.x, f3.y, f3.z, f3.w);
    w2t[d] = o;
}

// ---------------- router: 1 wave per token, shfl butterfly, no global atomics ----------------
// block = 4 waves x 2 tokens = 8 tokens; grid 1024. Per-block histogram -> bhist.
__global__ __launch_bounds__(256, 4) void router_kernel(
    const float* __restrict__ x, const float* __restrict__ gw,
    int8_t* __restrict__ xq, float* __restrict__ xs,
    int* __restrict__ bhist, int* __restrict__ rinfo, float2* __restrict__ wp,
    float* __restrict__ logits_out)
{
    const int t = threadIdx.x, lane = t & 63, wv = t >> 6;
    __shared__ int lhist[8];
    if (t < 8) lhist[t] = 0;
    __syncthreads();
    const float4* gw4 = (const float4*)gw;
#pragma unroll 1
    for (int i = 0; i < 2; i++) {
        const int token = blockIdx.x * 8 + wv * 2 + i;
        const float4* xrow = (const float4*)(x + (size_t)token * H_DIM);
        float4 xv[4];
#pragma unroll
        for (int j = 0; j < 4; j++) xv[j] = xrow[j * 64 + lane];
        float am = 0.0f;
#pragma unroll
        for (int j = 0; j < 4; j++)
            am = fmaxf(am, fmaxf(fmaxf(fabsf(xv[j].x), fabsf(xv[j].y)),
                                 fmaxf(fabsf(xv[j].z), fabsf(xv[j].w))));
        float l[8];
#pragma unroll
        for (int e = 0; e < 8; e++) {
            float d = 0.0f;
#pragma unroll
            for (int j = 0; j < 4; j++) {
                float4 g = gw4[e * 256 + j * 64 + lane];
                d += xv[j].x * g.x + xv[j].y * g.y + xv[j].z * g.z + xv[j].w * g.w;
            }
            l[e] = d;
        }
        // 64-lane butterfly: all lanes end with full sums / max (bitwise identical)
#pragma unroll
        for (int m = 1; m < 64; m <<= 1) {
#pragma unroll
            for (int e = 0; e < 8; e++) l[e] += __shfl_xor(l[e], m, 64);
            am = fmaxf(am, __shfl_xor(am, m, 64));
        }
        // top-2 on logits (monotone in softmax probs); static indexing only
        float v0 = l[0]; int i0 = 0;
#pragma unroll
        for (int e = 1; e < 8; e++) if (l[e] > v0) { v0 = l[e]; i0 = e; }
        float v1 = -3.4e38f; int i1 = 0;
#pragma unroll
        for (int e = 0; e < 8; e++) if (e != i0 && l[e] > v1) { v1 = l[e]; i1 = e; }
        const float tt = __expf(v1 - v0);
        const float w0 = 1.0f / (1.0f + tt);
        const float w1 = tt * w0;
        const float s = fmaxf(am, 1e-8f) / 127.0f;
        const float rs = 1.0f / s;
        int8_t* xqr = xq + (size_t)token * H_DIM;
#pragma unroll
        for (int j = 0; j < 4; j++) {
            char4 c;
            c.x = (signed char)fminf(fmaxf(rintf(xv[j].x * rs), -127.0f), 127.0f);
            c.y = (signed char)fminf(fmaxf(rintf(xv[j].y * rs), -127.0f), 127.0f);
            c.z = (signed char)fminf(fmaxf(rintf(xv[j].z * rs), -127.0f), 127.0f);
            c.w = (signed char)fminf(fmaxf(rintf(xv[j].w * rs), -127.0f), 127.0f);
            ((char4*)xqr)[j * 64 + lane] = c;
        }
        if (lane == 0) {
            xs[token] = s;
#pragma unroll
            for (int e = 0; e < 8; e++) logits_out[(size_t)token * 8 + e] = l[e];
            int r0 = atomicAdd(&lhist[i0], 1);   // LDS atomic, per-block only
            int r1 = atomicAdd(&lhist[i1], 1);
            rinfo[token] = i0 | (i1 << 3) | (r0 << 6) | (r1 << 10);
            wp[token] = make_float2(w0, w1);
        }
    }
    __syncthreads();
    if (t < 8) bhist[blockIdx.x * 8 + t] = lhist[t];
}

// ---------------- planner: parallel scan of bhist -> expert-local prefixes ----------------
__global__ __launch_bounds__(256) void planner_kernel(
    int* __restrict__ bhist, int* __restrict__ cnt, int* __restrict__ offs,
    int* __restrict__ ntile, int* __restrict__ wlist)
{
    __shared__ int sm[8 * 1060];   // [e][b + b/32 pad]
    __shared__ int tot[8];
    const int t = threadIdx.x;
#pragma unroll
    for (int k = 0; k < 32; k++) {
        int idx = k * 256 + t;
        int v = bhist[idx];
        int e = idx & 7, b = idx >> 3;
        sm[e * 1060 + b + (b >> 5)] = v;
    }
    __syncthreads();
    const int e = t >> 5, sub = t & 31;
    int* seg = sm + e * 1060 + sub * 33;     // b=sub*32+i -> sub*33+i
    int run = 0;
#pragma unroll
    for (int i = 0; i < 32; i++) { int v = seg[i]; seg[i] = run; run += v; }
    int inc = run;
#pragma unroll
    for (int d = 1; d < 32; d <<= 1) {
        int u = __shfl_up(inc, d, 32);
        if (sub >= d) inc += u;
    }
    const int segbase = inc - run;
    if (sub == 31) tot[e] = inc;
#pragma unroll
    for (int i = 0; i < 32; i++) seg[i] += segbase;
    __syncthreads();
    if (t == 0) {
        int s = 0, nt = 0;
        for (int ee = 0; ee < 8; ee++) {
            offs[ee] = s;
            int c = tot[ee];
            cnt[ee] = c;
            s += c;
            int tc = (c + 127) >> 7;
            for (int m = 0; m < tc; m++) wlist[nt++] = (ee << 8) | m;
        }
        *ntile = nt;
    }
#pragma unroll
    for (int k = 0; k < 32; k++) {
        int idx = k * 256 + t;
        int ee = idx & 7, b = idx >> 3;
        bhist[idx] = sm[ee * 1060 + b + (b >> 5)];
    }
}

// ---------------- scatter: finalize list/tw/tslot from prefixes ----------------
__global__ __launch_bounds__(256) void scatter_kernel(
    const int* __restrict__ bhist, const int* __restrict__ rinfo,
    const float2* __restrict__ wp, int* __restrict__ list,
    float* __restrict__ tw, int* __restrict__ tslot)
{
    const int token = blockIdx.x * 256 + threadIdx.x;
    const int ri = rinfo[token];
    const float2 wpr = wp[token];
    const int b = token >> 3;
    const int e0 = ri & 7, e1 = (ri >> 3) & 7;
    const int r0 = (ri >> 6) & 15, r1 = (ri >> 10) & 15;
    const int p0 = bhist[b * 8 + e0] + r0;
    const int p1 = bhist[b * 8 + e1] + r1;
    list[e0 * T_TOK + p0] = token;  tw[e0 * T_TOK + p0] = wpr.x;
    list[e1 * T_TOK + p1] = token;  tw[e1 * T_TOK + p1] = wpr.y;
    tslot[token * 2 + 0] = (e0 << 16) | p0;
    tslot[token * 2 + 1] = (e1 << 16) | p1;
}

// ---------------- activation gather: slot-ordered A tiles in slab layout ----------------
__global__ __launch_bounds__(256) void gather_kernel(
    const int8_t* __restrict__ xq, const float* __restrict__ xs,
    const int* __restrict__ cnt, const int* __restrict__ ntile_p,
    const int* __restrict__ wlist, const int* __restrict__ list,
    v4i* __restrict__ xg, float* __restrict__ xsg)
{
    const int bx = blockIdx.x;
    if (bx >= *ntile_p) return;
    const int wl = wlist[bx];
    const int e = wl >> 8, mt = wl & 255;
    const int count = cnt[e];
    const int cm1 = count - 1;
    const int t = threadIdx.x;
    const int* liste = list + e * T_TOK;
    __shared__ int stok[128];
    if (t < 128) {
        int p = mt * 128 + t;
        int tok = liste[p < count ? p : cm1];
        stok[t] = tok;
        xsg[bx * 128 + t] = xs[tok];
    }
    __syncthreads();
    v4i* dslab = xg + (size_t)bx * 8192;   // 16 slabs x 512 v4i
#pragma unroll
    for (int i = 0; i < 32; i++) {
        int flat = i * 256 + t;            // [row(128)][c(64 v4i)]
        int row = flat >> 6, c = flat & 63;
        v4i v = ((const v4i*)(xq + (size_t)stok[row] * H_DIM))[c];
        int kt = c >> 2, c16 = c & 3, rg = row >> 5, r = row & 31;
        dslab[kt * 512 + rg * 128 + c16 * 32 + r] = v;
    }
}

// ---------------- grouped GEMM1: depth-2 counted-vmcnt pipeline, BK=64 ----------------
// XCD-chunked (bx innermost) decode kept from R6 (FETCH collapsed to ~compulsory).
// 3 LDS buffers; s_waitcnt vmcnt(6) + raw s_barrier: stage(kt+1)'s 6 loads stay in
// flight across the barrier, so no per-step full drain.
__global__ __launch_bounds__(256, 2) void gemm1_kernel(
    const v4i* __restrict__ xg, const float* __restrict__ xsg,
    const v4i* __restrict__ w13t,
    const float* __restrict__ w1s, const float* __restrict__ w3s,
    const float* __restrict__ dscale,
    const int* __restrict__ cnt, const int* __restrict__ ntile_p,
    const int* __restrict__ wlist,
    int8_t* __restrict__ gbt)
{
    const int h = blockIdx.x + blockIdx.y * 136;        // 3808 = 8 * 476
    const int w476 = h >> 3;                            // position within XCD chunk
    const int ft  = w476 / 17;                          // 28 values, OUTER
    const int bxi = w476 - ft * 17;                     // 17 values, INNER
    const int bx  = (h & 7) * 17 + bxi;
    if (bx >= *ntile_p) return;
    const int wl = wlist[bx];
    const int e = wl >> 8, mt = wl & 255;
    const int count = cnt[e];
    const int t = threadIdx.x, lane = t & 63, w = t >> 6;
    const int wm = w >> 1, wn = w & 1;

    __shared__ v4i sm[4608];   // 3 buffers x [A 512 | B1 512 | B3 512] v4i = 72 KB
    char* smb = (char*)sm;

    const char* gA = (const char*)(xg + (size_t)bx * 8192) + w * 2048 + lane * 16;
    const char* gB = (const char*)(w13t + (size_t)(e * 28 + ft) * 16384) + lane * 16;
    const int wq = w * 2048;

    v16i acc1[2][2], acc3[2][2];
#pragma unroll
    for (int i = 0; i < 2; i++)
#pragma unroll
        for (int j = 0; j < 2; j++)
#pragma unroll
            for (int r = 0; r < 16; r++) { acc1[i][j][r] = 0; acc3[i][j][r] = 0; }

    auto stage = [&](int kt, int buf) {     // 6 wave-linear 1KB global_load_lds
        char* base = smb + buf * 24576;
        const char* sa = gA + kt * 8192;
        async16(sa,        base + wq);
        async16(sa + 1024, base + wq + 1024);
        const char* s1 = gB + (size_t)kt * 16384;
        async16(s1 + wq,               base + 8192 + wq);
        async16(s1 + wq + 1024,        base + 8192 + wq + 1024);
        async16(s1 + 8192 + wq,        base + 16384 + wq);
        async16(s1 + 8192 + wq + 1024, base + 16384 + wq + 1024);
    };
    auto compute = [&](int buf) {
        const v4i* S = sm + buf * 1536;
#pragma unroll
        for (int ks = 0; ks < 2; ks++) {
            const int base = (2 * ks + (lane >> 5)) * 32 + (lane & 31);
            v4i a0  = S[base + (wm * 2 + 0) * 128];
            v4i a1  = S[base + (wm * 2 + 1) * 128];
            v4i b1a = S[512 + base + (wn * 2 + 0) * 128];
            v4i b1b = S[512 + base + (wn * 2 + 1) * 128];
            v4i b3a = S[1024 + base + (wn * 2 + 0) * 128];
            v4i b3b = S[1024 + base + (wn * 2 + 1) * 128];
            acc1[0][0] = __builtin_amdgcn_mfma_i32_32x32x32_i8(a0, b1a, acc1[0][0], 0, 0, 0);
            acc1[0][1] = __builtin_amdgcn_mfma_i32_32x32x32_i8(a0, b1b, acc1[0][1], 0, 0, 0);
            acc1[1][0] = __builtin_amdgcn_mfma_i32_32x32x32_i8(a1, b1a, acc1[1][0], 0, 0, 0);
            acc1[1][1] = __builtin_amdgcn_mfma_i32_32x32x32_i8(a1, b1b, acc1[1][1], 0, 0, 0);
            acc3[0][0] = __builtin_amdgcn_mfma_i32_32x32x32_i8(a0, b3a, acc3[0][0], 0, 0, 0);
            acc3[0][1] = __builtin_amdgcn_mfma_i32_32x32x32_i8(a0, b3b, acc3[0][1], 0, 0, 0);
            acc3[1][0] = __builtin_amdgcn_mfma_i32_32x32x32_i8(a1, b3a, acc3[1][0], 0, 0, 0);
            acc3[1][1] = __builtin_amdgcn_mfma_i32_32x32x32_i8(a1, b3b, acc3[1][1], 0, 0, 0);
        }
    };

    // depth-2 pipeline: at iter kt, vmcnt(6) completes stage(kt) (oldest 6 of 12),
    // leaving stage(kt+1) in flight; barrier AFTER the wait makes all waves' stage(kt)
    // LDS slices visible (each wave writes its own slice; cross-wave reads need the
    // barrier-ordered vmcnt). stage(kt+2) is issued only after the barrier proving
    // all waves finished reading buffer (kt+2)%3 in compute(kt-1).
    stage(0, 0);
    stage(1, 1);
    int bufc = 0, bufs = 2;
    for (int kt = 0; kt < 15; kt++) {
        asm volatile("s_waitcnt vmcnt(6)" ::: "memory");
        __builtin_amdgcn_s_barrier();
        if (kt + 2 < 16) stage(kt + 2, bufs);
        compute(bufc);
        bufc = (bufc == 2) ? 0 : bufc + 1;
        bufs = (bufs == 2) ? 0 : bufs + 1;
    }
    asm volatile("s_waitcnt vmcnt(0)" ::: "memory");
    __builtin_amdgcn_s_barrier();
    compute(bufc);

    const float ds = dscale[e];
    const float rds = 1.0f / ds;
    int8_t* gout = gbt + (size_t)bx * 458752 + (size_t)(ft * 2 + wn) * 8192;
#pragma unroll
    for (int im = 0; im < 2; im++) {
#pragma unroll
        for (int in = 0; in < 2; in++) {
            const int fco = in * 32 + (lane & 31);
            const int fcol = ft * 128 + wn * 64 + fco;
            const float s1 = w1s[e * F_DIM + fcol];
            const float s3 = w3s[e * F_DIM + fcol];
            const int coff = ((in * 2 + ((lane & 31) >> 4)) * 32) * 16 + (lane & 15);
#pragma unroll
            for (int r = 0; r < 16; r++) {
                int row = wm * 64 + im * 32 + (r & 3) + 8 * (r >> 2) + 4 * (lane >> 5);
                int p = mt * 128 + row;
                if (p < count) {
                    float sx = xsg[bx * 128 + row];
                    float h1 = (float)acc1[im][in][r] * sx * s1;
                    float h3 = (float)acc3[im][in][r] * sx * s3;
                    float g = h1 * __builtin_amdgcn_rcpf(1.0f + __expf(-h1)) * h3;
                    float qv = fminf(fmaxf(rintf(g * rds), -127.0f), 127.0f);
                    gout[(size_t)((wm * 2 + im) * 128 + (row & 31)) * 16 + coff] = (int8_t)qv;
                }
            }
        }
    }
}

// ---------------- grouped GEMM2: depth-2 counted-vmcnt pipeline, BK=64 ----------------
// 3 buffers x 16KB = 48KB: occupancy unchanged (3 blocks/CU LDS-wise, reg-capped ~12 waves).
__global__ __launch_bounds__(256, 3) void gemm2_kernel(
    const int8_t* __restrict__ gbt, const v4i* __restrict__ w2t,
    const float* __restrict__ w2s, const float* __restrict__ dscale,
    const int* __restrict__ cnt, const int* __restrict__ offs,
    const int* __restrict__ ntile_p, const int* __restrict__ wlist,
    const float* __restrict__ tw, float* __restrict__ ybuf)
{
    const int h = blockIdx.x + blockIdx.y * 136;        // 1088 = 8 * 136
    const int wk = (h & 7) * 136 + (h >> 3);
    const int bx = wk >> 3;
    const int ht = wk & 7;
    if (bx >= *ntile_p) return;
    const int wl = wlist[bx];
    const int e = wl >> 8, mt = wl & 255;
    const int count = cnt[e];
    const int t = threadIdx.x, lane = t & 63, w = t >> 6;
    const int wm = w >> 1, wn = w & 1;

    __shared__ v4i sm[3072];   // 3 buffers x [A 512 | B 512] = 48 KB
    char* smb = (char*)sm;

    const char* gA = (const char*)gbt + (size_t)bx * 458752 + w * 2048 + lane * 16;
    const char* gB = (const char*)(w2t + (size_t)(e * 8 + ht) * 28672) + w * 2048 + lane * 16;

    v16i acc[2][2];
#pragma unroll
    for (int i = 0; i < 2; i++)
#pragma unroll
        for (int j = 0; j < 2; j++)
#pragma unroll
            for (int r = 0; r < 16; r++) acc[i][j][r] = 0;

    auto stage = [&](int kt, int buf) {     // 4 wave-linear 1KB global_load_lds
        char* base = smb + buf * 16384;
        const size_t ko = (size_t)kt * 8192;
        async16(gA + ko,        base + w * 2048);
        async16(gA + ko + 1024, base + w * 2048 + 1024);
        async16(gB + ko,        base + 8192 + w * 2048);
        async16(gB + ko + 1024, base + 8192 + w * 2048 + 1024);
    };
    auto compute = [&](int buf) {
        const v4i* S = sm + buf * 1024;
#pragma unroll
        for (int ks = 0; ks < 2; ks++) {
            const int base = (2 * ks + (lane >> 5)) * 32 + (lane & 31);
            v4i a0 = S[base + (wm * 2 + 0) * 128];
            v4i a1 = S[base + (wm * 2 + 1) * 128];
            v4i b0 = S[512 + base + (wn * 2 + 0) * 128];
            v4i b1 = S[512 + base + (wn * 2 + 1) * 128];
            acc[0][0] = __builtin_amdgcn_mfma_i32_32x32x32_i8(a0, b0, acc[0][0], 0, 0, 0);
            acc[0][1] = __builtin_amdgcn_mfma_i32_32x32x32_i8(a0, b1, acc[0][1], 0, 0, 0);
            acc[1][0] = __builtin_amdgcn_mfma_i32_32x32x32_i8(a1, b0, acc[1][0], 0, 0, 0);
            acc[1][1] = __builtin_amdgcn_mfma_i32_32x32x32_i8(a1, b1, acc[1][1], 0, 0, 0);
        }
    };

    stage(0, 0);
    stage(1, 1);
    int bufc = 0, bufs = 2;
    for (int kt = 0; kt < 55; kt++) {
        asm volatile("s_waitcnt vmcnt(4)" ::: "memory");
        __builtin_amdgcn_s_barrier();
        if (kt + 2 < 56) stage(kt + 2, bufs);
        compute(bufc);
        bufc = (bufc == 2) ? 0 : bufc + 1;
        bufs = (bufs == 2) ? 0 : bufs + 1;
    }
    asm volatile("s_waitcnt vmcnt(0)" ::: "memory");
    __builtin_amdgcn_s_barrier();
    compute(bufc);

    const float ds = dscale[e];
    const int rowbase = offs[e] + mt * 128;
#pragma unroll
    for (int im = 0; im < 2; im++) {
#pragma unroll
        for (int in = 0; in < 2; in++) {
            const int h2 = ht * 128 + wn * 64 + in * 32 + (lane & 31);
            const float sc = ds * w2s[e * H_DIM + h2];
#pragma unroll
            for (int r = 0; r < 16; r++) {
                int row = wm * 64 + im * 32 + (r & 3) + 8 * (r >> 2) + 4 * (lane >> 5);
                int p = mt * 128 + row;
                if (p < count) {
                    float rw = tw[e * T_TOK + p];
                    ybuf[(size_t)(rowbase + row) * H_DIM + h2] = (float)acc[im][in][r] * sc * rw;
                }
            }
        }
    }
}

// ---------------- combine ----------------
__global__ __launch_bounds__(256) void combine_kernel(
    const float* __restrict__ ybuf, const int* __restrict__ offs,
    const int* __restrict__ tslot, float* __restrict__ out)
{
    const int token = blockIdx.x;
    const int i = threadIdx.x;
    const int s0 = tslot[token * 2 + 0];
    const int s1 = tslot[token * 2 + 1];
    const int slot0 = offs[s0 >> 16] + (s0 & 0xffff);
    const int slot1 = offs[s1 >> 16] + (s1 & 0xffff);
    float4 a = ((const float4*)(ybuf + (size_t)slot0 * H_DIM))[i];
    float4 b = ((const float4*)(ybuf + (size_t)slot1 * H_DIM))[i];
    float4 o;
    o.x = a.x + b.x; o.y = a.y + b.y; o.z = a.z + b.z; o.w = a.w + b.w;
    ((float4*)(out + (size_t)token * H_DIM))[i] = o;
}

extern "C" void kernel_launch(void* const* d_in, const int* in_sizes, int n_in,
                              void* d_out, int out_size, void* d_ws, size_t ws_size,
                              hipStream_t stream)
{
    const float* x    = (const float*)d_in[0];
    const float* gw   = (const float*)d_in[1];
    const float* w1   = (const float*)d_in[2];
    const float* w1s  = (const float*)d_in[3];
    const float* w3   = (const float*)d_in[4];
    const float* w3s  = (const float*)d_in[5];
    const float* w2   = (const float*)d_in[6];
    const float* w2s  = (const float*)d_in[7];
    const float* dsc  = (const float*)d_in[8];

    float* out = (float*)d_out;
    float* logits_out = out + (size_t)T_TOK * H_DIM;

    char* ws = (char*)d_ws;
    v4i*    w13t = (v4i*)   (ws + W13T_OFF);
    int8_t* xq   = (int8_t*)(ws + XQ_OFF);
    v4i*    w2t  = (v4i*)   (ws + W2T_OFF);
    int8_t* gbt  = (int8_t*)(ws + GBT_OFF);
    float*  xs   = (float*) (ws + XS_OFF);
    int*    list = (int*)   (ws + LIST_OFF);
    float*  tws  = (float*) (ws + TW_OFF);
    int*    tslot= (int*)   (ws + TSLOT_OFF);
    int*    cnt  = (int*)   (ws + CNT_OFF);
    int*    offs = (int*)   (ws + OFFS_OFF);
    int*    ntile= (int*)   (ws + NT_OFF);
    int*    wlist= (int*)   (ws + WLIST_OFF);
    int*    rinfo= (int*)   (ws + RINFO_OFF);
    float2* wp   = (float2*)(ws + WP_OFF);
    int*    bhist= (int*)   (ws + BHIST_OFF);
    v4i*    xg   = (v4i*)   (ws + XG_OFF);
    float*  xsg  = (float*) (ws + XSG_OFF);
    float*  ybuf = (float*) (ws + YBUF_OFF);

    convert13_kernel<<<14336, 256, 0, stream>>>(w1, w3, w13t);
    router_kernel<<<1024, 256, 0, stream>>>(x, gw, xq, xs, bhist, rinfo, wp, logits_out);
    planner_kernel<<<1, 256, 0, stream>>>(bhist, cnt, offs, ntile, wlist);
    scatter_kernel<<<32, 256, 0, stream>>>(bhist, rinfo, wp, list, tws, tslot);
    gather_kernel<<<136, 256, 0, stream>>>(xq, xs, cnt, ntile, wlist, list, xg, xsg);
    gemm1_kernel<<<dim3(136, 28), 256, 0, stream>>>(
        xg, xsg, w13t, w1s, w3s, dsc, cnt, ntile, wlist, gbt);
    convert2_kernel<<<7168, 256, 0, stream>>>(w2, w2t);   // overwrites xg (dead)
    gemm2_kernel<<<dim3(136, 8), 256, 0, stream>>>(
        gbt, w2t, w2s, dsc, cnt, offs, ntile, wlist, tws, ybuf);
    combine_kernel<<<T_TOK, 256, 0, stream>>>(ybuf, offs, tslot, out);
}